// Round 6
// baseline (447.416 us; speedup 1.0000x reference)
//
#include <hip/hip_runtime.h>
#include <cfloat>

#define B_ 32
#define N_ 4096
#define C_ 768
#define T_ 1000
#define K_ 20

#define PXB 256           // pixels per k24 block (== threads)
#define PHC 16            // floats per c-phase (64 B per px per phase)
#define NPH (C_/PHC)      // 48 phases
#define NBLK 512          // k24 grid: 32 b x 16 tiles; exactly 2 blocks/CU co-resident
#define GAP_TH 1e-3f

typedef float f32x4 __attribute__((ext_vector_type(4)));

// ---------------- K1a: vg_logit in fp64 (+ zero cnt and grid-barrier) ----------------
__global__ __launch_bounds__(256) void k1_logits(const float* __restrict__ g_feat,
                                                 const float* __restrict__ text,
                                                 double* __restrict__ logits,
                                                 int* __restrict__ cnt,
                                                 int* __restrict__ bar) {
    int b = blockIdx.x;
    int wid = threadIdx.x >> 6, lane = threadIdx.x & 63;
    int t = blockIdx.y * 4 + wid;           // grid.y = 250 -> t in [0,1000)
    if (b == 0 && blockIdx.y == 0) {
        for (int i = threadIdx.x; i < B_ * K_; i += 256) cnt[i] = 0;
        if (threadIdx.x == 0) bar[0] = 0;
    }
    const float* g = g_feat + b * C_;
    const float* e = text + t * C_;
    double s = 0.0;
    #pragma unroll
    for (int j = 0; j < 12; ++j) {
        int c = lane + 64 * j;
        s += (double)g[c] * (double)e[c];
    }
    #pragma unroll
    for (int m = 32; m; m >>= 1) s += __shfl_xor(s, m);
    if (lane == 0) logits[b * T_ + t] = s;
}

// ---------------- K1b: top-20 per batch (1-wave shuffle select) + gather ----------------
__global__ __launch_bounds__(256) void k1b_topk(const double* __restrict__ logits,
                                                const float* __restrict__ text,
                                                float* __restrict__ agg) {
    __shared__ int ssel[K_];
    int b = blockIdx.x, tid = threadIdx.x, lane = tid & 63;
    if (tid < 64) {
        double v[16];
        #pragma unroll
        for (int j = 0; j < 16; ++j) {
            int t = lane + 64 * j;
            v[j] = (t < T_) ? logits[b * T_ + t] : -DBL_MAX;
        }
        for (int it = 0; it < K_; ++it) {
            double bv = -DBL_MAX; int bi = 0x7fffffff;
            #pragma unroll
            for (int j = 0; j < 16; ++j) {
                int t = lane + 64 * j;
                if (v[j] > bv) { bv = v[j]; bi = t; }
            }
            #pragma unroll
            for (int m = 32; m; m >>= 1) {
                double ov = __shfl_xor(bv, m); int oi = __shfl_xor(bi, m);
                if (ov > bv || (ov == bv && oi < bi)) { bv = ov; bi = oi; }
            }
            if (lane == 0) ssel[it] = bi;
            #pragma unroll
            for (int j = 0; j < 16; ++j) {
                int t = lane + 64 * j;
                if (t == bi) v[j] = -DBL_MAX;
            }
        }
    }
    __syncthreads();
    for (int i = tid; i < K_ * C_; i += 256) {
        int j = i / C_, c = i - j * C_;
        agg[b * K_ * C_ + i] = text[ssel[j] * C_ + c];
    }
}

// ---------------- K24: fused argmax + grid barrier + output write ----------------
// Phase 1: 256 px/block, 1 px/thread; 48 c-phases, 3-deep pipelined global_load_lds
//   (4 buffers), uniform 5 loads/wave/stage, counted s_waitcnt vmcnt(15).
//   f chunks at phys = c ^ ((c>>3)&7) (16B-chunk XOR: conflict-free ds_read_b128,
//   linear LDS dst for DMA, pre-swizzled global src).
// Epilogue: per-thread top-2; wave-parallel fp64 re-decision for gap < GAP_TH;
//   block cnt atomics -> device cnt.
// Grid barrier: arrival counter (512 blocks == exactly co-resident capacity at
//   74 KB LDS/block + VGPR<=128 via launch_bounds).
// Phase 2: block writes its own 256 rows: out[px] = agg[kidx[px]] * 1/(cnt+1).
__global__ __launch_bounds__(256, 2) void k24_fused(const float* __restrict__ feat,
                                                    const float* __restrict__ agg,
                                                    int* __restrict__ cnt,
                                                    int* __restrict__ bar,
                                                    float* __restrict__ out) {
    __shared__ float fbuf[4][PXB * PHC];      // 4 x 16 KB
    __shared__ float ebuf[4][512];            // 4 x 2 KB
    __shared__ int   kidxl[PXB];
    __shared__ float scs[K_];
    __shared__ int   scnt[K_];
    int bx = blockIdx.x;
    int b = bx >> 4, tile = bx & 15;
    int n0 = tile * PXB;
    int tid = threadIdx.x, wid = tid >> 6, lane = tid & 63;
    if (tid < K_) scnt[tid] = 0;              // first use is after many barriers

    const float* fb = feat + ((size_t)b * N_ + n0) * C_;
    const float* eb = agg + b * (K_ * C_);

    // e-staging: waves {0,2} cover chunks 0..63, waves {1,3} chunks 40..79 (dup-clamped)
    int ce = (wid & 1) * 40 + lane; if (ce > 79) ce = 79;
    const float* esrc = eb + (ce >> 2) * C_ + (ce & 3) * 4;
    int cl = lane ^ ((lane >> 3) & 7);        // in-window chunk permutation

    auto stage = [&](int p, int bufi) {
        #pragma unroll
        for (int ii = 0; ii < 4; ++ii) {
            int q = wid * 4 + ii;
            int c = q * 64 + cl;              // logical chunk this lane fetches
            int px = c >> 2, j = c & 3;
            const float* g = fb + (size_t)px * C_ + p * PHC + j * 4;
            float* d = &fbuf[bufi][q * 256];  // wave-uniform; HW adds lane*16
            __builtin_amdgcn_global_load_lds((const __attribute__((address_space(1))) void*)g,
                                             (__attribute__((address_space(3))) void*)d, 16, 0, 0);
        }
        {
            const float* g = esrc + p * PHC;
            float* d = &ebuf[bufi][(wid & 1) * 160];
            __builtin_amdgcn_global_load_lds((const __attribute__((address_space(1))) void*)g,
                                             (__attribute__((address_space(3))) void*)d, 16, 0, 0);
        }
    };

    float acc[K_];
    #pragma unroll
    for (int k = 0; k < K_; ++k) acc[k] = 0.f;

    stage(0, 0);
    stage(1, 1);
    stage(2, 2);

    #pragma unroll 1
    for (int p = 0; p < NPH; ++p) {
        int bufi = p & 3;
        if (p + 3 < NPH) {
            stage(p + 3, (p + 3) & 3);
            asm volatile("s_waitcnt vmcnt(15)" ::: "memory");   // stage p landed
        } else if (p + 2 < NPH) {
            asm volatile("s_waitcnt vmcnt(10)" ::: "memory");
        } else if (p + 1 < NPH) {
            asm volatile("s_waitcnt vmcnt(5)" ::: "memory");
        } else {
            asm volatile("s_waitcnt vmcnt(0)" ::: "memory");
        }
        asm volatile("s_barrier" ::: "memory");

        const float* fB = fbuf[bufi];
        const float* eB = ebuf[bufi];
        f32x4 F[4];
        #pragma unroll
        for (int j = 0; j < 4; ++j) {
            int c = tid * 4 + j, h = c ^ ((c >> 3) & 7);
            F[j] = *(const f32x4*)(fB + h * 4);
        }
        #pragma unroll
        for (int k = 0; k < K_; ++k) {
            float a = acc[k];
            #pragma unroll
            for (int j = 0; j < 4; ++j) {
                f32x4 e = *(const f32x4*)(eB + (k * 4 + j) * 4);  // broadcast
                a = fmaf(F[j].x, e.x, a);
                a = fmaf(F[j].y, e.y, a);
                a = fmaf(F[j].z, e.z, a);
                a = fmaf(F[j].w, e.w, a);
            }
            acc[k] = a;
        }
        asm volatile("s_barrier" ::: "memory");   // buf reuse protection
    }

    // ---- per-thread top-2 (first-max-wins == jnp.argmax) ----
    float m1 = acc[0]; int i1 = 0; float m2 = -FLT_MAX;
    #pragma unroll
    for (int k = 1; k < K_; ++k) {
        float v = acc[k];
        if (v > m1) { m2 = m1; m1 = v; i1 = k; }
        else if (v > m2) m2 = v;
    }

    // ---- wave-parallel fp64 re-decision for knife-edge pixels ----
    unsigned long long mask = __ballot(m1 - m2 < GAP_TH);
    while (mask) {
        int l = __ffsll(mask) - 1; mask &= mask - 1;
        int px = wid * 64 + l;
        const float* fr = feat + ((size_t)b * N_ + n0 + px) * C_;
        double fd[12];
        #pragma unroll
        for (int j = 0; j < 12; ++j) fd[j] = (double)fr[lane + 64 * j];
        double best = -DBL_MAX; int bi = 0;
        for (int k = 0; k < K_; ++k) {
            const float* er = eb + k * C_;
            double s = 0.0;
            #pragma unroll
            for (int j = 0; j < 12; ++j) s += fd[j] * (double)er[lane + 64 * j];
            #pragma unroll
            for (int m = 32; m; m >>= 1) s += __shfl_xor(s, m);
            if (s > best) { best = s; bi = k; }
        }
        if (lane == l) i1 = bi;
    }

    kidxl[tid] = i1;
    atomicAdd(&scnt[i1], 1);
    __syncthreads();                            // drains vmcnt before bar release
    if (tid < K_) atomicAdd(&cnt[b * K_ + tid], scnt[tid]);
    __syncthreads();                            // cnt atomics drained (vmcnt(0) at barrier)

    // ---- grid barrier (all 512 blocks co-resident by construction) ----
    if (tid == 0) {
        __hip_atomic_fetch_add(bar, 1, __ATOMIC_ACQ_REL, __HIP_MEMORY_SCOPE_AGENT);
        while (__hip_atomic_load(bar, __ATOMIC_ACQUIRE, __HIP_MEMORY_SCOPE_AGENT) < NBLK)
            __builtin_amdgcn_s_sleep(1);
    }
    __syncthreads();

    // ---- phase 2: scales, then stream out this block's 256 rows ----
    if (tid < K_) {
        int cv = __hip_atomic_load(&cnt[b * K_ + tid], __ATOMIC_RELAXED, __HIP_MEMORY_SCOPE_AGENT);
        scs[tid] = 1.0f / ((float)cv + 1.0f);   // exact int count -> matches ref
    }
    __syncthreads();

    const f32x4* agg4 = (const f32x4*)agg;
    f32x4* out4 = (f32x4*)out + (size_t)(b * N_ + n0) * (C_ / 4);
    #pragma unroll 1
    for (int i = 0; i < 64; i += 4) {
        int px0 = wid * 64 + i;
        int kks[4]; float s4[4];
        #pragma unroll
        for (int t = 0; t < 4; ++t) { kks[t] = kidxl[px0 + t]; s4[t] = scs[kks[t]]; }
        f32x4 v[4][3];
        #pragma unroll
        for (int t = 0; t < 4; ++t) {
            const f32x4* a4 = agg4 + (size_t)(b * K_ + kks[t]) * (C_ / 4);
            #pragma unroll
            for (int j = 0; j < 3; ++j) v[t][j] = a4[lane + 64 * j];
        }
        #pragma unroll
        for (int t = 0; t < 4; ++t) {
            #pragma unroll
            for (int j = 0; j < 3; ++j)
                out4[(size_t)(px0 + t) * (C_ / 4) + lane + 64 * j] = v[t][j] * s4[t];
        }
    }
}

extern "C" void kernel_launch(void* const* d_in, const int* in_sizes, int n_in,
                              void* d_out, int out_size, void* d_ws, size_t ws_size,
                              hipStream_t stream) {
    const float* g_feat = (const float*)d_in[0];
    const float* feat   = (const float*)d_in[1];
    // d_in[2] = tau: positive scale, numerically irrelevant (attn == y_hard exactly)
    const float* text   = (const float*)d_in[3];
    float* out = (float*)d_out;

    char* ws = (char*)d_ws;
    double* logits = (double*)(ws + 0);              // 256000 B
    float*  agg    = (float*) (ws + 262144);         // 1966080 B
    int*    cnt    = (int*)   (ws + 2230784);        // 2560 B
    int*    bar    = (int*)   (ws + 2233344);        // 64 B

    k1_logits<<<dim3(32, 250), 256, 0, stream>>>(g_feat, text, logits, cnt, bar);
    k1b_topk<<<32, 256, 0, stream>>>(logits, text, agg);
    k24_fused<<<NBLK, 256, 0, stream>>>(feat, agg, cnt, bar, out);
}

// Round 7
// 326.529 us; speedup vs baseline: 1.3702x; 1.3702x over previous
//
#include <hip/hip_runtime.h>
#include <cfloat>

#define B_ 32
#define N_ 4096
#define C_ 768
#define T_ 1000
#define K_ 20

#define PXB 256           // pixels per k2 block (== threads)
#define PHC 8             // floats per c-phase (32 B per px per phase)
#define NPH (C_/PHC)      // 96 phases
#define GAP_TH 1e-3f
#define MAXF 16384

typedef float f32x4 __attribute__((ext_vector_type(4)));

// ---------------- K1a: vg_logit in fp64 (+ zero counters) ----------------
__global__ __launch_bounds__(256) void k1_logits(const float* __restrict__ g_feat,
                                                 const float* __restrict__ text,
                                                 double* __restrict__ logits,
                                                 int* __restrict__ cnt,
                                                 int* __restrict__ flagcnt) {
    int b = blockIdx.x;
    int wid = threadIdx.x >> 6, lane = threadIdx.x & 63;
    int t = blockIdx.y * 4 + wid;           // grid.y = 250 -> t in [0,1000)
    if (b == 0 && blockIdx.y == 0) {
        for (int i = threadIdx.x; i < B_ * K_; i += 256) cnt[i] = 0;
        if (threadIdx.x == 0) flagcnt[0] = 0;
    }
    const float* g = g_feat + b * C_;
    const float* e = text + t * C_;
    double s = 0.0;
    #pragma unroll
    for (int j = 0; j < 12; ++j) {
        int c = lane + 64 * j;
        s += (double)g[c] * (double)e[c];
    }
    #pragma unroll
    for (int m = 32; m; m >>= 1) s += __shfl_xor(s, m);
    if (lane == 0) logits[b * T_ + t] = s;
}

// ---------------- K1b: top-20 per batch (1-wave shuffle select) + gather ----------------
__global__ __launch_bounds__(256) void k1b_topk(const double* __restrict__ logits,
                                                const float* __restrict__ text,
                                                float* __restrict__ agg) {
    __shared__ int ssel[K_];
    int b = blockIdx.x, tid = threadIdx.x, lane = tid & 63;
    if (tid < 64) {
        double v[16];
        #pragma unroll
        for (int j = 0; j < 16; ++j) {
            int t = lane + 64 * j;
            v[j] = (t < T_) ? logits[b * T_ + t] : -DBL_MAX;
        }
        for (int it = 0; it < K_; ++it) {
            double bv = -DBL_MAX; int bi = 0x7fffffff;
            #pragma unroll
            for (int j = 0; j < 16; ++j) {
                int t = lane + 64 * j;
                if (v[j] > bv) { bv = v[j]; bi = t; }
            }
            #pragma unroll
            for (int m = 32; m; m >>= 1) {
                double ov = __shfl_xor(bv, m); int oi = __shfl_xor(bi, m);
                if (ov > bv || (ov == bv && oi < bi)) { bv = ov; bi = oi; }
            }
            if (lane == 0) ssel[it] = bi;
            #pragma unroll
            for (int j = 0; j < 16; ++j) {
                int t = lane + 64 * j;
                if (t == bi) v[j] = -DBL_MAX;
            }
        }
    }
    __syncthreads();
    for (int i = tid; i < K_ * C_; i += 256) {
        int j = i / C_, c = i - j * C_;
        agg[b * K_ * C_ + i] = text[ssel[j] * C_ + c];
    }
}

// ---------------- K2: per-pixel argmax, 16 waves/CU, 3-deep pipelined staging ----------------
// 256 threads = 4 waves; 256 px/block; PHC=8 -> 96 phases. Per wave per stage:
// 2 f-DMA + 1 e-DMA (global_load_lds, 16B); quad buffer, counted vmcnt(9).
// 16B chunks stored at phys = c ^ ((c>>3)&7): conflict-free ds_read_b128 while
// LDS dst stays linear for DMA (source pre-swizzled; involution).
// LDS 36 KB + VGPR<=128 (launch_bounds(256,4)) -> 4 blocks/CU = 46% occupancy.
__global__ __launch_bounds__(256, 4) void k2_argmax(const float* __restrict__ feat,
                                                    const float* __restrict__ agg,
                                                    int* __restrict__ kidx,
                                                    int* __restrict__ cnt,
                                                    int* __restrict__ flagcnt,
                                                    int* __restrict__ flaglist) {
    __shared__ float fbuf[4][PXB * PHC];      // 4 x 8 KB (512 chunks of 16B each)
    __shared__ float ebuf[4][256];            // 4 x 1 KB (40 used + dup tail)
    __shared__ int scnt[K_];
    int bx = blockIdx.x;
    int b = bx >> 4, tile = bx & 15;
    int n0 = tile * PXB;
    int tid = threadIdx.x, wid = tid >> 6, lane = tid & 63;
    if (tid < K_) scnt[tid] = 0;
    __syncthreads();

    const float* fb = feat + ((size_t)b * N_ + n0) * C_;
    const float* eb = agg + b * (K_ * C_);

    // e chunk this lane stages: ce=(k,half), 40 chunks; lanes >=40 dup chunk 39.
    int ce = lane < 40 ? lane : 39;
    const float* esrc = eb + (ce >> 1) * C_ + (ce & 1) * 4;

    auto stage = [&](int p, int bufi) {
        #pragma unroll
        for (int ii = 0; ii < 2; ++ii) {
            int q = (wid * 2 + ii) * 64;          // phys chunk base for this DMA
            int s = q + lane;                     // phys 16B slot
            int c = s ^ ((s >> 3) & 7);           // logical chunk (involution)
            int px = c >> 1, half = c & 1;
            const float* g = fb + (size_t)px * C_ + p * PHC + half * 4;
            float* d = &fbuf[bufi][q * 4];        // wave-uniform; HW adds lane*16
            __builtin_amdgcn_global_load_lds((const __attribute__((address_space(1))) void*)g,
                                             (__attribute__((address_space(3))) void*)d, 16, 0, 0);
        }
        {   // all 4 waves dup-stage e (same data, benign)
            const float* g = esrc + p * PHC;
            float* d = &ebuf[bufi][0];
            __builtin_amdgcn_global_load_lds((const __attribute__((address_space(1))) void*)g,
                                             (__attribute__((address_space(3))) void*)d, 16, 0, 0);
        }
    };

    float acc[K_];
    #pragma unroll
    for (int k = 0; k < K_; ++k) acc[k] = 0.f;

    stage(0, 0);
    stage(1, 1);
    stage(2, 2);

    int c0 = tid * 2;                             // this px's even chunk
    int h0 = c0 ^ ((c0 >> 3) & 7);                // phys slots (h1 = h0^1)
    #pragma unroll 1
    for (int p = 0; p < NPH; ++p) {
        int bufi = p & 3;
        if (p + 3 < NPH) {
            stage(p + 3, (p + 3) & 3);
            asm volatile("s_waitcnt vmcnt(9)" ::: "memory");   // stage p's 3 landed
        } else if (p + 2 < NPH) {
            asm volatile("s_waitcnt vmcnt(6)" ::: "memory");
        } else if (p + 1 < NPH) {
            asm volatile("s_waitcnt vmcnt(3)" ::: "memory");
        } else {
            asm volatile("s_waitcnt vmcnt(0)" ::: "memory");
        }
        asm volatile("s_barrier" ::: "memory");

        const float* fB = fbuf[bufi];
        const float* eB = ebuf[bufi];
        f32x4 F0 = *(const f32x4*)(fB + h0 * 4);
        f32x4 F1 = *(const f32x4*)(fB + (h0 ^ 1) * 4);
        #pragma unroll
        for (int k = 0; k < K_; ++k) {
            f32x4 e0 = *(const f32x4*)(eB + (k * 2 + 0) * 4);   // broadcast
            f32x4 e1 = *(const f32x4*)(eB + (k * 2 + 1) * 4);
            float a = acc[k];
            a = fmaf(F0.x, e0.x, a); a = fmaf(F0.y, e0.y, a);
            a = fmaf(F0.z, e0.z, a); a = fmaf(F0.w, e0.w, a);
            a = fmaf(F1.x, e1.x, a); a = fmaf(F1.y, e1.y, a);
            a = fmaf(F1.z, e1.z, a); a = fmaf(F1.w, e1.w, a);
            acc[k] = a;
        }
        asm volatile("s_barrier" ::: "memory");   // buf reuse protection
    }

    // top-2 scan, first-max-wins (matches jnp.argmax)
    float m1 = acc[0]; int i1 = 0; float m2 = -FLT_MAX;
    #pragma unroll
    for (int k = 1; k < K_; ++k) {
        float v = acc[k];
        if (v > m1) { m2 = m1; m1 = v; i1 = k; }
        else if (v > m2) m2 = v;
    }
    int n = n0 + tid;
    kidx[b * N_ + n] = i1;
    atomicAdd(&scnt[i1], 1);
    if (m1 - m2 < GAP_TH) {
        int pos = atomicAdd(flagcnt, 1);
        if (pos < MAXF) flaglist[pos] = b * N_ + n;
    }
    __syncthreads();
    if (tid < K_) atomicAdd(&cnt[b * K_ + tid], scnt[tid]);
}

// ---------------- K2.5: fp64 re-decision for knife-edge pixels ----------------
__global__ __launch_bounds__(256) void k25_refine(const float* __restrict__ feat,
                                                  const float* __restrict__ agg,
                                                  int* __restrict__ kidx,
                                                  int* __restrict__ cnt,
                                                  const int* __restrict__ flagcnt,
                                                  const int* __restrict__ flaglist) {
    int wid = threadIdx.x >> 6, lane = threadIdx.x & 63;
    int wg = blockIdx.x * 4 + wid;
    int nf = flagcnt[0]; if (nf > MAXF) nf = MAXF;
    for (int e = wg; e < nf; e += gridDim.x * 4) {
        int pix = flaglist[e];
        int b = pix >> 12;
        const float* fr = feat + (size_t)pix * C_;
        const float* ebase = agg + b * K_ * C_;
        double fd[12];
        #pragma unroll
        for (int j = 0; j < 12; ++j) fd[j] = (double)fr[lane + 64 * j];
        double best = -DBL_MAX; int bi = 0;
        for (int k = 0; k < K_; ++k) {
            const float* er = ebase + k * C_;
            double s = 0.0;
            #pragma unroll
            for (int j = 0; j < 12; ++j) s += fd[j] * (double)er[lane + 64 * j];
            #pragma unroll
            for (int m = 32; m; m >>= 1) s += __shfl_xor(s, m);
            if (s > best) { best = s; bi = k; }
        }
        if (lane == 0) {
            int old = kidx[pix];
            if (old != bi) {
                kidx[pix] = bi;
                atomicSub(&cnt[b * K_ + old], 1);
                atomicAdd(&cnt[b * K_ + bi], 1);
            }
        }
    }
}

// ---------------- K4: broadcast-write output (8 px/wave, plain stores) ----------------
__global__ __launch_bounds__(256) void k4_out(const float* __restrict__ agg,
                                              const int* __restrict__ cnt,
                                              const int* __restrict__ kidx,
                                              float* __restrict__ out) {
    int wid = threadIdx.x >> 6, lane = threadIdx.x & 63;
    int wg = blockIdx.x * 4 + wid;          // 16384 waves, 8 px each
    int base = wg * 8;
    int b = base >> 12;                     // wave-uniform (8 | 4096)
    int kk[8];
    #pragma unroll
    for (int i = 0; i < 8; ++i) kk[i] = kidx[base + i];
    float sc[8];
    #pragma unroll
    for (int i = 0; i < 8; ++i) sc[i] = 1.0f / ((float)cnt[b * K_ + kk[i]] + 1.0f);
    const f32x4* agg4 = (const f32x4*)agg;
    f32x4* out4 = (f32x4*)out;
    #pragma unroll
    for (int i = 0; i < 8; ++i) {
        const f32x4* a4 = agg4 + (size_t)(b * K_ + kk[i]) * (C_ / 4);
        f32x4* o4 = out4 + (size_t)(base + i) * (C_ / 4);
        #pragma unroll
        for (int j = 0; j < 3; ++j) {
            f32x4 v = a4[lane + 64 * j];
            v *= sc[i];
            o4[lane + 64 * j] = v;
        }
    }
}

extern "C" void kernel_launch(void* const* d_in, const int* in_sizes, int n_in,
                              void* d_out, int out_size, void* d_ws, size_t ws_size,
                              hipStream_t stream) {
    const float* g_feat = (const float*)d_in[0];
    const float* feat   = (const float*)d_in[1];
    // d_in[2] = tau: positive scale, numerically irrelevant (attn == y_hard exactly)
    const float* text   = (const float*)d_in[3];
    float* out = (float*)d_out;

    char* ws = (char*)d_ws;
    double* logits = (double*)(ws + 0);              // 256000 B
    float*  agg    = (float*) (ws + 262144);         // 1966080 B
    int*    cnt    = (int*)   (ws + 2230784);        // 2560 B
    int*    flagc  = (int*)   (ws + 2233344);        // 64 B
    int*    flagl  = (int*)   (ws + 2233408);        // 65536 B
    int*    kidx   = (int*)   (ws + 2301504);        // 524288 B

    k1_logits<<<dim3(32, 250), 256, 0, stream>>>(g_feat, text, logits, cnt, flagc);
    k1b_topk<<<32, 256, 0, stream>>>(logits, text, agg);
    k2_argmax<<<32 * 16, 256, 0, stream>>>(feat, agg, kidx, cnt, flagc, flagl);
    k25_refine<<<64, 256, 0, stream>>>(feat, agg, kidx, cnt, flagc, flagl);
    k4_out<<<4096, 256, 0, stream>>>(agg, cnt, kidx, out);
}

// Round 8
// 273.501 us; speedup vs baseline: 1.6359x; 1.1939x over previous
//
#include <hip/hip_runtime.h>
#include <cfloat>

#define B_ 32
#define N_ 4096
#define C_ 768
#define T_ 1000
#define K_ 20

#define PXB 256           // pixels per k2 block
#define PHC 32            // floats per c-phase (one MFMA K=32 step)
#define NPH (C_/PHC)      // 24 phases
#define GAP_TH 1e-4f
#define MAXF 16384

typedef float f32x4 __attribute__((ext_vector_type(4)));
typedef int   i32x4 __attribute__((ext_vector_type(4)));
typedef short s16x8 __attribute__((ext_vector_type(8)));   // 8 bf16 (4 VGPR)

__device__ __forceinline__ unsigned short bf_rne(float x) {
    unsigned u = __float_as_uint(x);
    return (unsigned short)((u + 0x7fffu + ((u >> 16) & 1u)) >> 16);
}

// ---------------- K1a: vg_logit in fp64 (+ zero counters) ----------------
__global__ __launch_bounds__(256) void k1_logits(const float* __restrict__ g_feat,
                                                 const float* __restrict__ text,
                                                 double* __restrict__ logits,
                                                 int* __restrict__ cnt,
                                                 int* __restrict__ flagcnt) {
    int b = blockIdx.x;
    int wid = threadIdx.x >> 6, lane = threadIdx.x & 63;
    int t = blockIdx.y * 4 + wid;           // grid.y = 250 -> t in [0,1000)
    if (b == 0 && blockIdx.y == 0) {
        for (int i = threadIdx.x; i < B_ * K_; i += 256) cnt[i] = 0;
        if (threadIdx.x == 0) flagcnt[0] = 0;
    }
    const float* g = g_feat + b * C_;
    const float* e = text + t * C_;
    double s = 0.0;
    #pragma unroll
    for (int j = 0; j < 12; ++j) {
        int c = lane + 64 * j;
        s += (double)g[c] * (double)e[c];
    }
    #pragma unroll
    for (int m = 32; m; m >>= 1) s += __shfl_xor(s, m);
    if (lane == 0) logits[b * T_ + t] = s;
}

// ---------------- K1b: top-20 (1-wave shuffle select) + gather + bf16 hi/lo split ----------------
__global__ __launch_bounds__(256) void k1b_topk(const double* __restrict__ logits,
                                                const float* __restrict__ text,
                                                float* __restrict__ agg,
                                                unsigned short* __restrict__ Ehi,
                                                unsigned short* __restrict__ Elo) {
    __shared__ int ssel[K_];
    int b = blockIdx.x, tid = threadIdx.x, lane = tid & 63;
    if (tid < 64) {
        double v[16];
        #pragma unroll
        for (int j = 0; j < 16; ++j) {
            int t = lane + 64 * j;
            v[j] = (t < T_) ? logits[b * T_ + t] : -DBL_MAX;
        }
        for (int it = 0; it < K_; ++it) {
            double bv = -DBL_MAX; int bi = 0x7fffffff;
            #pragma unroll
            for (int j = 0; j < 16; ++j) {
                int t = lane + 64 * j;
                if (v[j] > bv) { bv = v[j]; bi = t; }
            }
            #pragma unroll
            for (int m = 32; m; m >>= 1) {
                double ov = __shfl_xor(bv, m); int oi = __shfl_xor(bi, m);
                if (ov > bv || (ov == bv && oi < bi)) { bv = ov; bi = oi; }
            }
            if (lane == 0) ssel[it] = bi;
            #pragma unroll
            for (int j = 0; j < 16; ++j) {
                int t = lane + 64 * j;
                if (t == bi) v[j] = -DBL_MAX;
            }
        }
    }
    __syncthreads();
    for (int i = tid; i < K_ * C_; i += 256) {
        int j = i / C_, c = i - j * C_;
        agg[b * K_ * C_ + i] = text[ssel[j] * C_ + c];
    }
    // E split: rows 0..19 real, 20..31 zero. hi = trunc16, lo = rne(v - hi).
    for (int i = tid; i < 32 * C_; i += 256) {
        int r = i / C_, c = i - r * C_;
        float v = (r < K_) ? text[ssel[r] * C_ + c] : 0.f;
        unsigned u = __float_as_uint(v);
        float fh = __uint_as_float(u & 0xffff0000u);
        Ehi[(size_t)b * 32 * C_ + i] = (unsigned short)(u >> 16);
        Elo[(size_t)b * 32 * C_ + i] = bf_rne(v - fh);
    }
}

// ---------------- K2: per-pixel argmax via bf16-split MFMA ----------------
// S[b] = E(20x768) . F(px x 768)^T as 3-term bf16 MFMA (16x16x32), fp32 acc.
// 256 px/block, 4 waves, each wave owns 4 px-tiles of 16. Per phase (C-step 32):
// reg-stage F (8 dwordx4/thread) -> hi/lo cvt -> XOR-rotated ds_write_b128
// (bank floor); A-frags (E hi/lo, both k-tiles) straight from L2-hot global.
// Double-buffered LDS, asm barriers, loads stay in flight across barriers.
__global__ __launch_bounds__(256, 2) void k2_argmax(const float* __restrict__ feat,
                                                    const unsigned short* __restrict__ Ehi,
                                                    const unsigned short* __restrict__ Elo,
                                                    int* __restrict__ kidx,
                                                    int* __restrict__ cnt,
                                                    int* __restrict__ flagcnt,
                                                    int* __restrict__ flaglist) {
    __shared__ unsigned short hiT[2][PXB * PHC];   // 2 x 16 KB, [px][4 slots of 8 bf16]
    __shared__ unsigned short loT[2][PXB * PHC];   // 2 x 16 KB
    __shared__ int scnt[K_];
    int bx = blockIdx.x;
    int b = bx >> 4, tile = bx & 15;
    int n0 = tile * PXB;
    int tid = threadIdx.x, wid = tid >> 6, lane = tid & 63;
    if (tid < K_) scnt[tid] = 0;
    __syncthreads();

    const float* fb = feat + ((size_t)b * N_ + n0) * C_;
    const unsigned short* Eh = Ehi + (size_t)b * 32 * C_;
    const unsigned short* El = Elo + (size_t)b * 32 * C_;
    int r2 = (tid >> 1) & 3;                 // write-rotation key (bank floor)
    int arow = lane & 15, acg = lane >> 4;   // A-frag row / k-group

    f32x4 fr[8];
    auto LOADF = [&](int p) {
        const f32x4* fp_ = (const f32x4*)(fb + (size_t)tid * C_ + p * PHC);
        #pragma unroll
        for (int q = 0; q < 8; ++q) fr[q] = fp_[q ^ (2 * r2)];
    };
    auto CVTW = [&](int buf) {
        #pragma unroll
        for (int j = 0; j < 4; ++j) {
            unsigned hu[8], lu[8];
            #pragma unroll
            for (int m = 0; m < 8; ++m) {
                float x = (m < 4) ? fr[2 * j][m] : fr[2 * j + 1][m - 4];
                unsigned u = __float_as_uint(x);
                float fh = __uint_as_float(u & 0xffff0000u);
                hu[m] = u >> 16;
                lu[m] = bf_rne(x - fh);
            }
            int slot = tid * 4 + (j ^ r2);
            i32x4 hv = { (int)(hu[0] | (hu[1] << 16)), (int)(hu[2] | (hu[3] << 16)),
                         (int)(hu[4] | (hu[5] << 16)), (int)(hu[6] | (hu[7] << 16)) };
            i32x4 lv = { (int)(lu[0] | (lu[1] << 16)), (int)(lu[2] | (lu[3] << 16)),
                         (int)(lu[4] | (lu[5] << 16)), (int)(lu[6] | (lu[7] << 16)) };
            *(i32x4*)&hiT[buf][slot * 8] = hv;
            *(i32x4*)&loT[buf][slot * 8] = lv;
        }
    };

    s16x8 Ach0, Ach1, Acl0, Acl1, Anh0, Anh1, Anl0, Anl1;
    auto LOADA = [&](int p, s16x8& h0, s16x8& h1, s16x8& l0, s16x8& l1) {
        int co = p * PHC + acg * 8;
        h0 = *(const s16x8*)(Eh + (size_t)arow * C_ + co);
        h1 = *(const s16x8*)(Eh + (size_t)(16 + arow) * C_ + co);
        l0 = *(const s16x8*)(El + (size_t)arow * C_ + co);
        l1 = *(const s16x8*)(El + (size_t)(16 + arow) * C_ + co);
    };

    f32x4 acc0[4], acc1[4];
    #pragma unroll
    for (int i = 0; i < 4; ++i) { acc0[i] = (f32x4)0.f; acc1[i] = (f32x4)0.f; }

    // prologue
    LOADF(0);
    CVTW(0);
    LOADF(1);
    LOADA(0, Ach0, Ach1, Acl0, Acl1);
    LOADA(1, Anh0, Anh1, Anl0, Anl1);
    __syncthreads();

    #pragma unroll 1
    for (int p = 0; p < NPH; ++p) {
        int cur = p & 1;
        if (p + 1 < NPH) {
            CVTW(cur ^ 1);                    // F(p+1) -> other buffer
            if (p + 2 < NPH) LOADF(p + 2);    // issue next loads (in flight across barriers)
            asm volatile("s_waitcnt lgkmcnt(0)" ::: "memory");
        }
        asm volatile("s_barrier" ::: "memory");

        #pragma unroll
        for (int i = 0; i < 4; ++i) {
            int slot = (wid * 64 + i * 16 + arow) * 4 + acg;
            s16x8 Bh = *(const s16x8*)&hiT[cur][slot * 8];
            s16x8 Bl = *(const s16x8*)&loT[cur][slot * 8];
            acc0[i] = __builtin_amdgcn_mfma_f32_16x16x32_bf16(Ach0, Bh, acc0[i], 0, 0, 0);
            acc1[i] = __builtin_amdgcn_mfma_f32_16x16x32_bf16(Ach1, Bh, acc1[i], 0, 0, 0);
            acc0[i] = __builtin_amdgcn_mfma_f32_16x16x32_bf16(Ach0, Bl, acc0[i], 0, 0, 0);
            acc1[i] = __builtin_amdgcn_mfma_f32_16x16x32_bf16(Ach1, Bl, acc1[i], 0, 0, 0);
            acc0[i] = __builtin_amdgcn_mfma_f32_16x16x32_bf16(Acl0, Bh, acc0[i], 0, 0, 0);
            acc1[i] = __builtin_amdgcn_mfma_f32_16x16x32_bf16(Acl1, Bh, acc1[i], 0, 0, 0);
        }
        asm volatile("s_barrier" ::: "memory");

        Ach0 = Anh0; Ach1 = Anh1; Acl0 = Anl0; Acl1 = Anl1;
        if (p + 2 < NPH) LOADA(p + 2, Anh0, Anh1, Anl0, Anl1);
    }

    // epilogue: per px-tile top-2 over k (C/D layout: col=lane&15=px, row=(lane>>4)*4+reg)
    #pragma unroll
    for (int i = 0; i < 4; ++i) {
        int kb = acg * 4;
        float m1 = acc0[i][0]; int i1 = kb; float m2 = -FLT_MAX;
        #pragma unroll
        for (int r = 1; r < 4; ++r) {
            float v = acc0[i][r];
            if (v > m1) { m2 = m1; m1 = v; i1 = kb + r; }
            else if (v > m2) m2 = v;
        }
        if (acg == 0) {                      // k-tile 1: only k=16..19 valid
            #pragma unroll
            for (int r = 0; r < 4; ++r) {
                float v = acc1[i][r];
                if (v > m1) { m2 = m1; m1 = v; i1 = 16 + r; }
                else if (v > m2) m2 = v;
            }
        }
        #pragma unroll
        for (int s = 16; s < 64; s <<= 1) {
            float om1 = __shfl_xor(m1, s); int oi1 = __shfl_xor(i1, s);
            float om2 = __shfl_xor(m2, s);
            if (om1 > m1 || (om1 == m1 && oi1 < i1)) { m2 = fmaxf(m1, om2); m1 = om1; i1 = oi1; }
            else { m2 = fmaxf(m2, om1); }
        }
        if (lane < 16) {
            int n = n0 + wid * 64 + i * 16 + lane;
            kidx[b * N_ + n] = i1;
            atomicAdd(&scnt[i1], 1);
            if (m1 - m2 < GAP_TH) {
                int pos = atomicAdd(flagcnt, 1);
                if (pos < MAXF) flaglist[pos] = b * N_ + n;
            }
        }
    }
    __syncthreads();
    if (tid < K_) atomicAdd(&cnt[b * K_ + tid], scnt[tid]);
}

// ---------------- K2.5: fp64 re-decision for knife-edge pixels ----------------
__global__ __launch_bounds__(256) void k25_refine(const float* __restrict__ feat,
                                                  const float* __restrict__ agg,
                                                  int* __restrict__ kidx,
                                                  int* __restrict__ cnt,
                                                  const int* __restrict__ flagcnt,
                                                  const int* __restrict__ flaglist) {
    int wid = threadIdx.x >> 6, lane = threadIdx.x & 63;
    int wg = blockIdx.x * 4 + wid;
    int nf = flagcnt[0]; if (nf > MAXF) nf = MAXF;
    for (int e = wg; e < nf; e += gridDim.x * 4) {
        int pix = flaglist[e];
        int b = pix >> 12;
        const float* fr = feat + (size_t)pix * C_;
        const float* ebase = agg + b * K_ * C_;
        double fd[12];
        #pragma unroll
        for (int j = 0; j < 12; ++j) fd[j] = (double)fr[lane + 64 * j];
        double best = -DBL_MAX; int bi = 0;
        for (int k = 0; k < K_; ++k) {
            const float* er = ebase + k * C_;
            double s = 0.0;
            #pragma unroll
            for (int j = 0; j < 12; ++j) s += fd[j] * (double)er[lane + 64 * j];
            #pragma unroll
            for (int m = 32; m; m >>= 1) s += __shfl_xor(s, m);
            if (s > best) { best = s; bi = k; }
        }
        if (lane == 0) {
            int old = kidx[pix];
            if (old != bi) {
                kidx[pix] = bi;
                atomicSub(&cnt[b * K_ + old], 1);
                atomicAdd(&cnt[b * K_ + bi], 1);
            }
        }
    }
}

// ---------------- K4: broadcast-write output (8 px/wave, plain stores) ----------------
__global__ __launch_bounds__(256) void k4_out(const float* __restrict__ agg,
                                              const int* __restrict__ cnt,
                                              const int* __restrict__ kidx,
                                              float* __restrict__ out) {
    int wid = threadIdx.x >> 6, lane = threadIdx.x & 63;
    int wg = blockIdx.x * 4 + wid;          // 16384 waves, 8 px each
    int base = wg * 8;
    int b = base >> 12;                     // wave-uniform (8 | 4096)
    int kk[8];
    #pragma unroll
    for (int i = 0; i < 8; ++i) kk[i] = kidx[base + i];
    float sc[8];
    #pragma unroll
    for (int i = 0; i < 8; ++i) sc[i] = 1.0f / ((float)cnt[b * K_ + kk[i]] + 1.0f);
    const f32x4* agg4 = (const f32x4*)agg;
    f32x4* out4 = (f32x4*)out;
    #pragma unroll
    for (int i = 0; i < 8; ++i) {
        const f32x4* a4 = agg4 + (size_t)(b * K_ + kk[i]) * (C_ / 4);
        f32x4* o4 = out4 + (size_t)(base + i) * (C_ / 4);
        #pragma unroll
        for (int j = 0; j < 3; ++j) {
            f32x4 v = a4[lane + 64 * j];
            v *= sc[i];
            o4[lane + 64 * j] = v;
        }
    }
}

extern "C" void kernel_launch(void* const* d_in, const int* in_sizes, int n_in,
                              void* d_out, int out_size, void* d_ws, size_t ws_size,
                              hipStream_t stream) {
    const float* g_feat = (const float*)d_in[0];
    const float* feat   = (const float*)d_in[1];
    // d_in[2] = tau: positive scale, numerically irrelevant (attn == y_hard exactly)
    const float* text   = (const float*)d_in[3];
    float* out = (float*)d_out;

    char* ws = (char*)d_ws;
    double* logits        = (double*)(ws + 0);         // 256000 B
    float*  agg           = (float*) (ws + 262144);    // 1966080 B
    int*    cnt           = (int*)   (ws + 2230784);   // 2560 B
    int*    flagc         = (int*)   (ws + 2233344);   // 64 B
    int*    flagl         = (int*)   (ws + 2233408);   // 65536 B
    int*    kidx          = (int*)   (ws + 2301504);   // 524288 B
    unsigned short* Ehi   = (unsigned short*)(ws + 2825792);  // 1572864 B
    unsigned short* Elo   = (unsigned short*)(ws + 4398656);  // 1572864 B

    k1_logits<<<dim3(32, 250), 256, 0, stream>>>(g_feat, text, logits, cnt, flagc);
    k1b_topk<<<32, 256, 0, stream>>>(logits, text, agg, Ehi, Elo);
    k2_argmax<<<32 * 16, 256, 0, stream>>>(feat, Ehi, Elo, kidx, cnt, flagc, flagl);
    k25_refine<<<1024, 256, 0, stream>>>(feat, agg, kidx, cnt, flagc, flagl);
    k4_out<<<4096, 256, 0, stream>>>(agg, cnt, kidx, out);
}